// Round 2
// baseline (686.682 us; speedup 1.0000x reference)
//
#include <hip/hip_runtime.h>
#include <math.h>

// Problem dims (fixed by setup_inputs)
constexpr int L  = 16384;   // 32*32*16 spatial
constexpr int LC = 64;      // scan chunk length
constexpr int NC = 256;     // L / LC chunks

__device__ __forceinline__ float sigm(float x){ return 1.0f/(1.0f+__expf(-x)); }
__device__ __forceinline__ float softplus_(float x){ return (x>20.0f)? x : log1pf(__expf(x)); }

// block-wide {sum, sumsq} accumulation into global via atomics (256-thread blocks)
__device__ __forceinline__ void block_accum2(float s, float s2, float* g0, float* g1){
    #pragma unroll
    for (int m=1;m<64;m<<=1){ s += __shfl_xor(s,m,64); s2 += __shfl_xor(s2,m,64); }
    __shared__ float red[16];
    int lane = threadIdx.x & 63, wid = threadIdx.x >> 6;
    if (lane==0){ red[wid]=s; red[8+wid]=s2; }
    __syncthreads();
    if (threadIdx.x==0){
        int nw = blockDim.x >> 6;
        float a=0.f,b=0.f;
        for (int i=0;i<nw;i++){ a+=red[i]; b+=red[8+i]; }
        atomicAdd(g0,a); atomicAdd(g1,b);
    }
}

// ---------------- Mamba branch ----------------

// LayerNorm over 32 channels per position + in_proj (32 -> 128). blockIdx.y picks a 32-wide j group.
__global__ void k_ln_proj(const float* __restrict__ x, const float* __restrict__ g,
                          const float* __restrict__ b, const float* __restrict__ w,
                          float* __restrict__ xi, float* __restrict__ z)
{
    int l = blockIdx.x*blockDim.x + threadIdx.x;
    int j0 = blockIdx.y*32;
    float xn[32]; float s=0.f, s2=0.f;
    #pragma unroll
    for (int c=0;c<32;c++){ float v = x[(32+c)*L + l]; xn[c]=v; s+=v; s2+=v*v; }
    float mu  = s*(1.0f/32.0f);
    float var = s2*(1.0f/32.0f) - mu*mu;
    float inv = rsqrtf(var + 1e-5f);
    #pragma unroll
    for (int c=0;c<32;c++) xn[c] = (xn[c]-mu)*inv*g[c] + b[c];
    for (int j=j0;j<j0+32;j++){
        float acc=0.f;
        #pragma unroll
        for (int c=0;c<32;c++) acc += w[j*32+c]*xn[c];
        if (j<64) xi[j*L+l]      = acc;   // xi layout [d][l]
        else      z[l*64+(j-64)] = acc;   // z layout [l][d]
    }
}

// depthwise causal conv1d + SiLU + x_proj + dt_proj(softplus), both directions (blockIdx.y)
__global__ void k_conv_proj(const float* __restrict__ xi,
    const float* __restrict__ cwf, const float* __restrict__ cbf,
    const float* __restrict__ xwf, const float* __restrict__ dwf, const float* __restrict__ dbf,
    const float* __restrict__ cwb, const float* __restrict__ cbb,
    const float* __restrict__ xwb, const float* __restrict__ dwb, const float* __restrict__ dbb,
    float* __restrict__ uf, float* __restrict__ dlf, float* __restrict__ Bfp, float* __restrict__ Cfp,
    float* __restrict__ ub, float* __restrict__ dlb, float* __restrict__ Bbp, float* __restrict__ Cbp)
{
    int l = blockIdx.x*blockDim.x + threadIdx.x;
    int gd = blockIdx.y;
    const float* cw = gd? cwb:cwf; const float* cb = gd? cbb:cbf;
    const float* xw = gd? xwb:xwf; const float* dw = gd? dwb:dwf; const float* db = gd? dbb:dbf;
    float* up = gd? ub:uf; float* dp = gd? dlb:dlf;
    float* Bp = gd? Bbp:Bfp; float* Cp = gd? Cbp:Cfp;

    float u[64];
    #pragma unroll
    for (int d=0; d<64; d++){
        float s = cb[d];
        #pragma unroll
        for (int k=0;k<4;k++){
            int j = l-3+k;                       // position in (possibly reversed) sequence
            float v = 0.0f;
            if (j>=0) v = xi[d*L + (gd ? (L-1-j) : j)];
            s += cw[d*4+k]*v;
        }
        u[d] = s*sigm(s);                        // SiLU
    }
    #pragma unroll
    for (int d=0; d<64; d++) up[l*64+d] = u[d];

    float dt0=0.f, dt1=0.f;
    #pragma unroll
    for (int d=0; d<64; d++){ dt0 += xw[d]*u[d]; dt1 += xw[64+d]*u[d]; }
    for (int n=0;n<16;n++){
        float bv=0.f, cv=0.f;
        #pragma unroll
        for (int d=0; d<64; d++){ bv += xw[(2+n)*64+d]*u[d]; cv += xw[(18+n)*64+d]*u[d]; }
        Bp[l*16+n]=bv; Cp[l*16+n]=cv;
    }
    #pragma unroll
    for (int d=0; d<64; d++){
        float t = dt0*dw[d*2] + dt1*dw[d*2+1] + db[d];
        dp[l*64+d] = softplus_(t);
    }
}

// scan pass 1: per-chunk aggregates (prod of dA, end state with h_in = 0)
__global__ void k_scan1(const float* __restrict__ dlf, const float* __restrict__ Bf, const float* __restrict__ ufp,
                        const float* __restrict__ dlb, const float* __restrict__ Bb, const float* __restrict__ ubp,
                        const float* __restrict__ Af, const float* __restrict__ Ab,
                        float* __restrict__ chA, float* __restrict__ chB)
{
    int tid = threadIdx.x;                 // d*16+n
    int c = blockIdx.x, gd = blockIdx.y;
    const float* dl = gd? dlb:dlf; const float* Bv = gd? Bb:Bf; const float* u = gd? ubp:ufp;
    float A = -__expf((gd? Ab:Af)[tid]);
    int d = tid>>4, n = tid&15;
    float h=0.f, p=1.f;
    int base = c*LC;
    #pragma unroll 4
    for (int i=0;i<LC;i++){
        int l = base+i;
        float dv = dl[l*64+d];
        float da = __expf(dv*A);
        float bu = dv * Bv[l*16+n] * u[l*64+d];
        h = da*h + bu;
        p *= da;
    }
    int o = (gd*NC + c)*1024 + tid;
    chA[o]=p; chB[o]=h;
}

// scan of chunk aggregates -> incoming state per chunk
__global__ void k_scan_agg(const float* __restrict__ chA, const float* __restrict__ chB,
                           float* __restrict__ hst)
{
    int tid = threadIdx.x; int gd = blockIdx.x;
    float h=0.f;
    #pragma unroll 8
    for (int c=0;c<NC;c++){
        int o = (gd*NC + c)*1024 + tid;
        hst[o]=h;
        h = chA[o]*h + chB[o];
    }
}

// scan pass 2: replay with correct h_in, emit y (+ u*D); backward writes reversed
__global__ void k_scan2(const float* __restrict__ dlf, const float* __restrict__ Bf,
                        const float* __restrict__ Cf, const float* __restrict__ ufp,
                        const float* __restrict__ dlb, const float* __restrict__ Bb,
                        const float* __restrict__ Cb, const float* __restrict__ ubp,
                        const float* __restrict__ Af, const float* __restrict__ Ab,
                        const float* __restrict__ Dfp, const float* __restrict__ Dbp,
                        const float* __restrict__ hst,
                        float* __restrict__ yf, float* __restrict__ yb)
{
    int tid = threadIdx.x;
    int c = blockIdx.x, gd = blockIdx.y;
    const float* dl = gd? dlb:dlf; const float* Bv = gd? Bb:Bf;
    const float* Cv = gd? Cb:Cf;  const float* u  = gd? ubp:ufp;
    float A = -__expf((gd? Ab:Af)[tid]);
    int d = tid>>4, n = tid&15;
    float Dd = (gd? Dbp:Dfp)[d];
    float h = hst[(gd*NC + c)*1024 + tid];
    int base = c*LC;
    for (int i=0;i<LC;i++){
        int l = base+i;
        float dv = dl[l*64+d];
        float uu = u[l*64+d];
        float da = __expf(dv*A);
        h = da*h + dv * Bv[l*16+n] * uu;
        float t = h * Cv[l*16+n];
        t += __shfl_xor(t,1,16); t += __shfl_xor(t,2,16);
        t += __shfl_xor(t,4,16); t += __shfl_xor(t,8,16);
        if (n==0){
            float r = t + uu*Dd;
            if (gd) yb[(L-1-l)*64+d] = r;
            else    yf[l*64+d]       = r;
        }
    }
}

// silu(z)*(yf+yb) @ out_proj^T  -> x_mamba [32][L]
__global__ void k_combine(const float* __restrict__ yf, const float* __restrict__ yb,
                          const float* __restrict__ z, const float* __restrict__ opw,
                          float* __restrict__ xm)
{
    int l = blockIdx.x*blockDim.x + threadIdx.x;
    int j0 = blockIdx.y*16;
    float yv[64];
    #pragma unroll
    for (int d=0;d<64;d++){
        float zv = z[l*64+d];
        yv[d] = (yf[l*64+d]+yb[l*64+d]) * (zv*sigm(zv));
    }
    for (int j=j0;j<j0+16;j++){
        float acc=0.f;
        #pragma unroll
        for (int d=0;d<64;d++) acc += opw[j*64+d]*yv[d];
        xm[j*L+l]=acc;
    }
}

// ---------------- conv3d branch ----------------

// 1x1x1 conv (32->32) + per-channel {sum,sumsq} stats (used for cp1 and cp2)
__global__ void k_conv1x1(const float* __restrict__ in, const float* __restrict__ w,
                          const float* __restrict__ b, float* __restrict__ out,
                          float* __restrict__ st)
{
    int oc = blockIdx.x; int l0 = blockIdx.y*(L/8);
    float s=0.f, s2=0.f;
    for (int l=l0+threadIdx.x; l<l0+L/8; l+=256){
        float acc = b[oc];
        #pragma unroll
        for (int ic=0;ic<32;ic++) acc += w[oc*32+ic]*in[ic*L+l];
        out[oc*L+l]=acc; s+=acc; s2+=acc*acc;
    }
    block_accum2(s,s2, st+oc, st+32+oc);
}

// instance-norm (stats already summed) + leaky relu, in place
__global__ void k_norm(float* __restrict__ buf, const float* __restrict__ st)
{
    int oc = blockIdx.x; int l0 = blockIdx.y*(L/8);
    float mu  = st[oc]*(1.0f/(float)L);
    float var = st[32+oc]*(1.0f/(float)L) - mu*mu;
    float inv = rsqrtf(var + 1e-5f);
    for (int l=l0+threadIdx.x; l<l0+L/8; l+=256){
        float v = (buf[oc*L+l]-mu)*inv;
        buf[oc*L+l] = (v>=0.0f)? v : 0.1f*v;
    }
}

// the 4 ELK convs (3x3x3, 5x1x1, 1x5x1, 1x1x5), 32->16 each; blockIdx.y selects 8-oc group
__global__ void k_elk(const float* __restrict__ h,
                      const float* __restrict__ w1, const float* __restrict__ b1,
                      const float* __restrict__ w2, const float* __restrict__ b2,
                      const float* __restrict__ w3, const float* __restrict__ b3,
                      const float* __restrict__ w4, const float* __restrict__ b4,
                      float* __restrict__ e)
{
    int l = blockIdx.x*64 + threadIdx.x;
    int oc0 = blockIdx.y*8;
    int zx = l>>9, yy=(l>>4)&31, xx=l&15;
    float a1[8],a2[8],a3[8],a4[8];
    #pragma unroll
    for (int o=0;o<8;o++){ a1[o]=b1[oc0+o]; a2[o]=b2[oc0+o]; a3[o]=b3[oc0+o]; a4[o]=b4[oc0+o]; }

    for (int ic=0; ic<32; ic++){
        const float* hc = h + ic*L;
        float in3[27];
        #pragma unroll
        for (int dz=0;dz<3;dz++)
        #pragma unroll
        for (int dy=0;dy<3;dy++)
        #pragma unroll
        for (int dx=0;dx<3;dx++){
            int zz=zx+dz-1, y2=yy+dy-1, x2=xx+dx-1;
            bool ok = ((unsigned)zz<32u) && ((unsigned)y2<32u) && ((unsigned)x2<16u);
            in3[(dz*3+dy)*3+dx] = ok ? hc[(zz<<9)+(y2<<4)+x2] : 0.0f;
        }
        #pragma unroll
        for (int o=0;o<8;o++){
            const float* wp = w1 + ((oc0+o)*32+ic)*27;
            float a=a1[o];
            #pragma unroll
            for (int t=0;t<27;t++) a += wp[t]*in3[t];
            a1[o]=a;
        }
        float i5[5];
        #pragma unroll
        for (int t=0;t<5;t++){ int zz=zx+t-2; i5[t] = ((unsigned)zz<32u)? hc[(zz<<9)+(yy<<4)+xx] : 0.0f; }
        #pragma unroll
        for (int o=0;o<8;o++){
            const float* wp = w2 + ((oc0+o)*32+ic)*5;
            float a=a2[o];
            #pragma unroll
            for (int t=0;t<5;t++) a += wp[t]*i5[t];
            a2[o]=a;
        }
        #pragma unroll
        for (int t=0;t<5;t++){ int y2=yy+t-2; i5[t] = ((unsigned)y2<32u)? hc[(zx<<9)+(y2<<4)+xx] : 0.0f; }
        #pragma unroll
        for (int o=0;o<8;o++){
            const float* wp = w3 + ((oc0+o)*32+ic)*5;
            float a=a3[o];
            #pragma unroll
            for (int t=0;t<5;t++) a += wp[t]*i5[t];
            a3[o]=a;
        }
        #pragma unroll
        for (int t=0;t<5;t++){ int x2=xx+t-2; i5[t] = ((unsigned)x2<16u)? hc[(zx<<9)+(yy<<4)+x2] : 0.0f; }
        #pragma unroll
        for (int o=0;o<8;o++){
            const float* wp = w4 + ((oc0+o)*32+ic)*5;
            float a=a4[o];
            #pragma unroll
            for (int t=0;t<5;t++) a += wp[t]*i5[t];
            a4[o]=a;
        }
    }
    #pragma unroll
    for (int o=0;o<8;o++){
        e[(oc0+o)*L+l]      = a1[o];
        e[(16+oc0+o)*L+l]   = a2[o];
        e[(32+oc0+o)*L+l]   = a3[o];
        e[(48+oc0+o)*L+l]   = a4[o];
    }
}

// elk5 (1x1x1, 64->32) + residual + stats
__global__ void k_elk5(const float* __restrict__ e, const float* __restrict__ hres,
                       const float* __restrict__ w, const float* __restrict__ b,
                       float* __restrict__ h2, float* __restrict__ st)
{
    int oc = blockIdx.x; int l0 = blockIdx.y*(L/8);
    float s=0.f, s2=0.f;
    for (int l=l0+threadIdx.x; l<l0+L/8; l+=256){
        float acc = b[oc];
        #pragma unroll
        for (int m=0;m<64;m++) acc += w[oc*64+m]*e[m*L+l];
        acc += hres[oc*L+l];
        h2[oc*L+l]=acc; s+=acc; s2+=acc*acc;
    }
    block_accum2(s,s2, st+oc, st+32+oc);
}

// ---------------- fusion ----------------

__global__ void k_pool(const float* __restrict__ h3, const float* __restrict__ xm,
                       float* __restrict__ pooled)
{
    int fc = blockIdx.x; int l0 = blockIdx.y*(L/8);
    const float* src = (fc&1) ? xm + (fc>>1)*L : h3 + (fc>>1)*L;
    float s=0.f;
    for (int l=l0+threadIdx.x; l<l0+L/8; l+=256) s += src[l];
    #pragma unroll
    for (int m=1;m<64;m<<=1) s += __shfl_xor(s,m,64);
    __shared__ float red[4];
    int lane = threadIdx.x&63, wid = threadIdx.x>>6;
    if (lane==0) red[wid]=s;
    __syncthreads();
    if (threadIdx.x==0) atomicAdd(pooled+fc, red[0]+red[1]+red[2]+red[3]);
}

__global__ void k_attn(const float* __restrict__ pooled, const float* __restrict__ aw,
                       float* __restrict__ attn)
{
    __shared__ float pl[64];
    int t = threadIdx.x;
    pl[t] = pooled[t]*(1.0f/(float)L);
    __syncthreads();
    float acc=0.f;
    #pragma unroll
    for (int c=0;c<64;c++) acc += aw[t*64+c]*pl[c];
    attn[t] = sigm(sigm(acc));
}

__global__ void k_final(const float* __restrict__ h3, const float* __restrict__ xm,
                        const float* __restrict__ attn, const float* __restrict__ w1,
                        const float* __restrict__ c2w, const float* __restrict__ c2b,
                        float* __restrict__ out)
{
    int l = blockIdx.x*blockDim.x + threadIdx.x;
    int o0 = blockIdx.y*16;
    float f[64];
    #pragma unroll
    for (int i=0;i<32;i++){ f[2*i] = h3[i*L+l]; f[2*i+1] = xm[i*L+l]; }
    float a2 = c2b[0];
    #pragma unroll
    for (int c=0;c<64;c++){
        int fc = (c<32) ? 2*c : 2*(c-32)+1;   // xcat order -> fused (interleaved) order
        a2 += c2w[c]*f[fc];
    }
    float at2 = sigm(a2);
    #pragma unroll
    for (int c=0;c<64;c++) f[c] *= attn[c];
    for (int o=o0;o<o0+16;o++){
        float acc=0.f;
        #pragma unroll
        for (int c=0;c<64;c++) acc += w1[o*64+c]*f[c];
        out[o*L+l] = acc*at2;
    }
}

// ---------------- launch ----------------

extern "C" void kernel_launch(void* const* d_in, const int* in_sizes, int n_in,
                              void* d_out, int out_size, void* d_ws, size_t ws_size,
                              hipStream_t stream)
{
    const float* x         = (const float*)d_in[0];
    const float* ln_g      = (const float*)d_in[1];
    const float* ln_b      = (const float*)d_in[2];
    const float* in_proj_w = (const float*)d_in[3];
    const float* conv1d_w  = (const float*)d_in[4];
    const float* conv1d_b  = (const float*)d_in[5];
    const float* x_proj_w  = (const float*)d_in[6];
    const float* dt_proj_w = (const float*)d_in[7];
    const float* dt_proj_b = (const float*)d_in[8];
    const float* A_log     = (const float*)d_in[9];
    const float* D_f       = (const float*)d_in[10];
    const float* conv1db_w = (const float*)d_in[11];
    const float* conv1db_b = (const float*)d_in[12];
    const float* x_projb_w = (const float*)d_in[13];
    const float* dt_projb_w= (const float*)d_in[14];
    const float* dt_projb_b= (const float*)d_in[15];
    const float* Ab_log    = (const float*)d_in[16];
    const float* D_b       = (const float*)d_in[17];
    const float* out_proj_w= (const float*)d_in[18];
    const float* cp1_w     = (const float*)d_in[19];
    const float* cp1_b     = (const float*)d_in[20];
    const float* elk1_w    = (const float*)d_in[21];
    const float* elk1_b    = (const float*)d_in[22];
    const float* elk2_w    = (const float*)d_in[23];
    const float* elk2_b    = (const float*)d_in[24];
    const float* elk3_w    = (const float*)d_in[25];
    const float* elk3_b    = (const float*)d_in[26];
    const float* elk4_w    = (const float*)d_in[27];
    const float* elk4_b    = (const float*)d_in[28];
    const float* elk5_w    = (const float*)d_in[29];
    const float* elk5_b    = (const float*)d_in[30];
    const float* cp2_w     = (const float*)d_in[31];
    const float* cp2_b     = (const float*)d_in[32];
    const float* atten_w   = (const float*)d_in[33];
    const float* conv1_w   = (const float*)d_in[34];
    const float* conv2_w   = (const float*)d_in[35];
    const float* conv2_b   = (const float*)d_in[36];

    float* ws = (float*)d_ws;
    // workspace layout (floats)
    float* XI  = ws + 0;          // [64][L]
    float* Z   = ws + 1048576;    // [L][64]
    float* UF  = ws + 2097152;    // [L][64]
    float* UB  = ws + 3145728;
    float* DLF = ws + 4194304;    // [L][64]
    float* DLB = ws + 5242880;
    float* BF  = ws + 6291456;    // [L][16]
    float* CF  = ws + 6553600;
    float* BB  = ws + 6815744;
    float* CB  = ws + 7077888;
    float* CHA = ws + 7340032;    // [2][NC][1024]
    float* CHB = ws + 7864320;
    float* HST = ws + 8388608;
    float* YF  = ws + 8912896;    // [L][64]
    float* YB  = ws + 9961472;
    float* XM  = ws + 11010048;   // [32][L]
    float* H1  = ws + 11534336;   // [32][L]
    float* E4  = ws + 12058624;   // [64][L]
    float* H2  = ws + 13107200;
    float* H3  = ws + 13631488;
    float* ST  = ws + 14155776;   // stats1[64] stats2[64] stats3[64] pooled[64] attn[64]

    hipMemsetAsync(ST, 0, 256*sizeof(float), stream);

    // mamba branch
    k_ln_proj<<<dim3(L/256,4), 256, 0, stream>>>(x, ln_g, ln_b, in_proj_w, XI, Z);
    k_conv_proj<<<dim3(L/256,2), 256, 0, stream>>>(XI,
        conv1d_w, conv1d_b, x_proj_w, dt_proj_w, dt_proj_b,
        conv1db_w, conv1db_b, x_projb_w, dt_projb_w, dt_projb_b,
        UF, DLF, BF, CF, UB, DLB, BB, CB);
    k_scan1<<<dim3(NC,2), 1024, 0, stream>>>(DLF, BF, UF, DLB, BB, UB, A_log, Ab_log, CHA, CHB);
    k_scan_agg<<<2, 1024, 0, stream>>>(CHA, CHB, HST);
    k_scan2<<<dim3(NC,2), 1024, 0, stream>>>(DLF, BF, CF, UF, DLB, BB, CB, UB,
                                             A_log, Ab_log, D_f, D_b, HST, YF, YB);
    k_combine<<<dim3(L/256,2), 256, 0, stream>>>(YF, YB, Z, out_proj_w, XM);

    // conv3d branch
    k_conv1x1<<<dim3(32,8), 256, 0, stream>>>(x, cp1_w, cp1_b, H1, ST);
    k_norm<<<dim3(32,8), 256, 0, stream>>>(H1, ST);
    k_elk<<<dim3(L/64,2), 64, 0, stream>>>(H1, elk1_w, elk1_b, elk2_w, elk2_b,
                                           elk3_w, elk3_b, elk4_w, elk4_b, E4);
    k_elk5<<<dim3(32,8), 256, 0, stream>>>(E4, H1, elk5_w, elk5_b, H2, ST+64);
    k_norm<<<dim3(32,8), 256, 0, stream>>>(H2, ST+64);
    k_conv1x1<<<dim3(32,8), 256, 0, stream>>>(H2, cp2_w, cp2_b, H3, ST+128);
    k_norm<<<dim3(32,8), 256, 0, stream>>>(H3, ST+128);

    // fusion
    k_pool<<<dim3(64,8), 256, 0, stream>>>(H3, XM, ST+192);
    k_attn<<<1, 64, 0, stream>>>(ST+192, atten_w, ST+256);
    k_final<<<dim3(L/256,4), 256, 0, stream>>>(H3, XM, ST+256, conv1_w, conv2_w, conv2_b,
                                               (float*)d_out);
}

// Round 3
// 491.156 us; speedup vs baseline: 1.3981x; 1.3981x over previous
//
#include <hip/hip_runtime.h>
#include <math.h>

// Problem dims (fixed by setup_inputs)
constexpr int L  = 16384;   // 32*32*16 spatial (z=32, y=32, x=16)
constexpr int LC = 64;      // scan chunk length
constexpr int NC = 256;     // L / LC chunks

// padded volume for ELK convs: halo 2 on every side
constexpr int PX = 20, PY = 36, PZ = 36;
constexpr int PSY = PX;            // y stride
constexpr int PSZ = PY*PX;         // z stride = 720
constexpr int PCH = PZ*PSZ;        // channel stride = 25920

__device__ __forceinline__ float sigm(float x){ return 1.0f/(1.0f+__expf(-x)); }
__device__ __forceinline__ float softplus_(float x){ return (x>20.0f)? x : log1pf(__expf(x)); }

// block-wide {sum, sumsq} accumulation into global via atomics (256-thread blocks)
__device__ __forceinline__ void block_accum2(float s, float s2, float* g0, float* g1){
    #pragma unroll
    for (int m=1;m<64;m<<=1){ s += __shfl_xor(s,m,64); s2 += __shfl_xor(s2,m,64); }
    __shared__ float red[16];
    int lane = threadIdx.x & 63, wid = threadIdx.x >> 6;
    if (lane==0){ red[wid]=s; red[8+wid]=s2; }
    __syncthreads();
    if (threadIdx.x==0){
        int nw = blockDim.x >> 6;
        float a=0.f,b=0.f;
        for (int i=0;i<nw;i++){ a+=red[i]; b+=red[8+i]; }
        atomicAdd(g0,a); atomicAdd(g1,b);
    }
}

// ---------------- Mamba branch ----------------

// LayerNorm over 32 channels per position + in_proj (32 -> 128). blockIdx.y picks a 32-wide j group.
__global__ __launch_bounds__(256,2)
void k_ln_proj(const float* __restrict__ x, const float* __restrict__ g,
               const float* __restrict__ b, const float* __restrict__ w,
               float* __restrict__ xi, float* __restrict__ z)
{
    int l = blockIdx.x*blockDim.x + threadIdx.x;
    int j0 = blockIdx.y*32;
    float xn[32]; float s=0.f, s2=0.f;
    #pragma unroll
    for (int c=0;c<32;c++){ float v = x[(32+c)*L + l]; xn[c]=v; s+=v; s2+=v*v; }
    float mu  = s*(1.0f/32.0f);
    float var = s2*(1.0f/32.0f) - mu*mu;
    float inv = rsqrtf(var + 1e-5f);
    #pragma unroll
    for (int c=0;c<32;c++) xn[c] = (xn[c]-mu)*inv*g[c] + b[c];
    for (int j=j0;j<j0+32;j++){
        float acc=0.f;
        #pragma unroll
        for (int c=0;c<32;c++) acc += w[j*32+c]*xn[c];
        if (j<64) xi[j*L+l]      = acc;   // xi layout [d][l]
        else      z[l*64+(j-64)] = acc;   // z layout [l][d]
    }
}

// depthwise causal conv1d + SiLU + x_proj + dt_proj(softplus), both directions (blockIdx.y)
// d-chunked: u consumed 16 at a time; B/C/dt accumulated incrementally -> no 64-wide array.
__global__ __launch_bounds__(256,2)
void k_conv_proj(const float* __restrict__ xi,
    const float* __restrict__ cwf, const float* __restrict__ cbf,
    const float* __restrict__ xwf, const float* __restrict__ dwf, const float* __restrict__ dbf,
    const float* __restrict__ cwb, const float* __restrict__ cbb,
    const float* __restrict__ xwb, const float* __restrict__ dwb, const float* __restrict__ dbb,
    float* __restrict__ uf, float* __restrict__ dlf, float* __restrict__ Bfp, float* __restrict__ Cfp,
    float* __restrict__ ub, float* __restrict__ dlb, float* __restrict__ Bbp, float* __restrict__ Cbp)
{
    int l = blockIdx.x*blockDim.x + threadIdx.x;
    int gd = blockIdx.y;
    const float* cw = gd? cwb:cwf; const float* cb = gd? cbb:cbf;
    const float* xw = gd? xwb:xwf; const float* dw = gd? dwb:dwf; const float* db = gd? dbb:dbf;
    float* up = gd? ub:uf; float* dp = gd? dlb:dlf;
    float* Bp = gd? Bbp:Bfp; float* Cp = gd? Cbp:Cfp;

    float dt0=0.f, dt1=0.f;
    float bacc[16], cacc[16];
    #pragma unroll
    for (int n=0;n<16;n++){ bacc[n]=0.f; cacc[n]=0.f; }

    #pragma unroll
    for (int dc=0; dc<4; dc++){
        #pragma unroll
        for (int dd=0; dd<16; dd++){
            int d = dc*16+dd;
            float s = cb[d];
            #pragma unroll
            for (int k=0;k<4;k++){
                int j = l-3+k;                       // position in (possibly reversed) sequence
                float v = 0.0f;
                if (j>=0) v = xi[d*L + (gd ? (L-1-j) : j)];
                s += cw[d*4+k]*v;
            }
            float u = s*sigm(s);                     // SiLU
            up[l*64+d] = u;
            dt0 += xw[d]*u; dt1 += xw[64+d]*u;
            #pragma unroll
            for (int n=0;n<16;n++){
                bacc[n] += xw[(2+n)*64+d]*u;
                cacc[n] += xw[(18+n)*64+d]*u;
            }
        }
    }
    #pragma unroll
    for (int n=0;n<16;n++){ Bp[l*16+n]=bacc[n]; Cp[l*16+n]=cacc[n]; }
    #pragma unroll
    for (int d=0; d<64; d++){
        float t = dt0*dw[d*2] + dt1*dw[d*2+1] + db[d];
        dp[l*64+d] = softplus_(t);
    }
}

// scan pass 1: per-chunk aggregates (prod of dA, end state with h_in = 0)
__global__ void k_scan1(const float* __restrict__ dlf, const float* __restrict__ Bf, const float* __restrict__ ufp,
                        const float* __restrict__ dlb, const float* __restrict__ Bb, const float* __restrict__ ubp,
                        const float* __restrict__ Af, const float* __restrict__ Ab,
                        float* __restrict__ chA, float* __restrict__ chB)
{
    int tid = threadIdx.x;                 // d*16+n
    int c = blockIdx.x, gd = blockIdx.y;
    const float* dl = gd? dlb:dlf; const float* Bv = gd? Bb:Bf; const float* u = gd? ubp:ufp;
    float A = -__expf((gd? Ab:Af)[tid]);
    int d = tid>>4, n = tid&15;
    float h=0.f, p=1.f;
    int base = c*LC;
    #pragma unroll 4
    for (int i=0;i<LC;i++){
        int l = base+i;
        float dv = dl[l*64+d];
        float da = __expf(dv*A);
        float bu = dv * Bv[l*16+n] * u[l*64+d];
        h = da*h + bu;
        p *= da;
    }
    int o = (gd*NC + c)*1024 + tid;
    chA[o]=p; chB[o]=h;
}

// scan of chunk aggregates -> incoming state per chunk
__global__ void k_scan_agg(const float* __restrict__ chA, const float* __restrict__ chB,
                           float* __restrict__ hst)
{
    int tid = threadIdx.x; int gd = blockIdx.x;
    float h=0.f;
    #pragma unroll 8
    for (int c=0;c<NC;c++){
        int o = (gd*NC + c)*1024 + tid;
        hst[o]=h;
        h = chA[o]*h + chB[o];
    }
}

// scan pass 2: replay with correct h_in, emit y (+ u*D); backward writes reversed
__global__ void k_scan2(const float* __restrict__ dlf, const float* __restrict__ Bf,
                        const float* __restrict__ Cf, const float* __restrict__ ufp,
                        const float* __restrict__ dlb, const float* __restrict__ Bb,
                        const float* __restrict__ Cb, const float* __restrict__ ubp,
                        const float* __restrict__ Af, const float* __restrict__ Ab,
                        const float* __restrict__ Dfp, const float* __restrict__ Dbp,
                        const float* __restrict__ hst,
                        float* __restrict__ yf, float* __restrict__ yb)
{
    int tid = threadIdx.x;
    int c = blockIdx.x, gd = blockIdx.y;
    const float* dl = gd? dlb:dlf; const float* Bv = gd? Bb:Bf;
    const float* Cv = gd? Cb:Cf;  const float* u  = gd? ubp:ufp;
    float A = -__expf((gd? Ab:Af)[tid]);
    int d = tid>>4, n = tid&15;
    float Dd = (gd? Dbp:Dfp)[d];
    float h = hst[(gd*NC + c)*1024 + tid];
    int base = c*LC;
    for (int i=0;i<LC;i++){
        int l = base+i;
        float dv = dl[l*64+d];
        float uu = u[l*64+d];
        float da = __expf(dv*A);
        h = da*h + dv * Bv[l*16+n] * uu;
        float t = h * Cv[l*16+n];
        t += __shfl_xor(t,1,16); t += __shfl_xor(t,2,16);
        t += __shfl_xor(t,4,16); t += __shfl_xor(t,8,16);
        if (n==0){
            float r = t + uu*Dd;
            if (gd) yb[(L-1-l)*64+d] = r;
            else    yf[l*64+d]       = r;
        }
    }
}

// silu(z)*(yf+yb) @ out_proj^T  -> x_mamba [32][L], chunked accumulators
__global__ __launch_bounds__(256,2)
void k_combine(const float* __restrict__ yf, const float* __restrict__ yb,
               const float* __restrict__ z, const float* __restrict__ opw,
               float* __restrict__ xm)
{
    int l = blockIdx.x*blockDim.x + threadIdx.x;
    int j0 = blockIdx.y*16;
    float acc[16];
    #pragma unroll
    for (int j=0;j<16;j++) acc[j]=0.f;
    #pragma unroll
    for (int dc=0; dc<4; dc++){
        #pragma unroll
        for (int dd=0; dd<16; dd++){
            int d = dc*16+dd;
            float zv = z[l*64+d];
            float yv = (yf[l*64+d]+yb[l*64+d]) * (zv*sigm(zv));
            #pragma unroll
            for (int j=0;j<16;j++) acc[j] += opw[(j0+j)*64+d]*yv;
        }
    }
    #pragma unroll
    for (int j=0;j<16;j++) xm[(j0+j)*L+l]=acc[j];
}

// ---------------- conv3d branch ----------------

// 1x1x1 conv (32->32) + per-channel {sum,sumsq} stats (used for cp1 and cp2)
__global__ void k_conv1x1(const float* __restrict__ in, const float* __restrict__ w,
                          const float* __restrict__ b, float* __restrict__ out,
                          float* __restrict__ st)
{
    int oc = blockIdx.x; int l0 = blockIdx.y*(L/8);
    float s=0.f, s2=0.f;
    for (int l=l0+threadIdx.x; l<l0+L/8; l+=256){
        float acc = b[oc];
        #pragma unroll
        for (int ic=0;ic<32;ic++) acc += w[oc*32+ic]*in[ic*L+l];
        out[oc*L+l]=acc; s+=acc; s2+=acc*acc;
    }
    block_accum2(s,s2, st+oc, st+32+oc);
}

// instance-norm (stats already summed) + leaky relu, in place
__global__ void k_norm(float* __restrict__ buf, const float* __restrict__ st)
{
    int oc = blockIdx.x; int l0 = blockIdx.y*(L/8);
    float mu  = st[oc]*(1.0f/(float)L);
    float var = st[32+oc]*(1.0f/(float)L) - mu*mu;
    float inv = rsqrtf(var + 1e-5f);
    for (int l=l0+threadIdx.x; l<l0+L/8; l+=256){
        float v = (buf[oc*L+l]-mu)*inv;
        buf[oc*L+l] = (v>=0.0f)? v : 0.1f*v;
    }
}

// instance-norm + lrelu for H1, writing both in-place (residual use) and a zero-padded copy
__global__ void k_norm_pad(float* __restrict__ buf, const float* __restrict__ st,
                           float* __restrict__ pad)
{
    int oc = blockIdx.x; int l0 = blockIdx.y*(L/8);
    float mu  = st[oc]*(1.0f/(float)L);
    float var = st[32+oc]*(1.0f/(float)L) - mu*mu;
    float inv = rsqrtf(var + 1e-5f);
    for (int l=l0+threadIdx.x; l<l0+L/8; l+=256){
        float v = (buf[oc*L+l]-mu)*inv;
        v = (v>=0.0f)? v : 0.1f*v;
        buf[oc*L+l] = v;
        int zx = l>>9, yy=(l>>4)&31, xx=l&15;
        pad[oc*PCH + (zx+2)*PSZ + (yy+2)*PSY + (xx+2)] = v;
    }
}

// the 4 ELK convs (3x3x3, 5x1x1, 1x5x1, 1x1x5), 32->16 each, on padded input.
// 256-thread blocks; blockIdx.y selects a 2-oc group -> grid (64, 8).
__global__ __launch_bounds__(256,2)
void k_elk(const float* __restrict__ hp,
           const float* __restrict__ w1, const float* __restrict__ b1,
           const float* __restrict__ w2, const float* __restrict__ b2,
           const float* __restrict__ w3, const float* __restrict__ b3,
           const float* __restrict__ w4, const float* __restrict__ b4,
           float* __restrict__ e)
{
    int l = blockIdx.x*256 + threadIdx.x;
    int oc0 = blockIdx.y*2;
    int zx = l>>9, yy=(l>>4)&31, xx=l&15;
    const float* base = hp + (zx+2)*PSZ + (yy+2)*PSY + (xx+2);
    float a1[2],a2[2],a3[2],a4[2];
    #pragma unroll
    for (int o=0;o<2;o++){ a1[o]=b1[oc0+o]; a2[o]=b2[oc0+o]; a3[o]=b3[oc0+o]; a4[o]=b4[oc0+o]; }

    for (int ic=0; ic<32; ic++){
        const float* hb = base + ic*PCH;
        float in3[27];
        #pragma unroll
        for (int dz=0;dz<3;dz++)
        #pragma unroll
        for (int dy=0;dy<3;dy++)
        #pragma unroll
        for (int dx=0;dx<3;dx++)
            in3[(dz*3+dy)*3+dx] = hb[(dz-1)*PSZ + (dy-1)*PSY + (dx-1)];
        float z5[5], y5[5], x5[5];
        #pragma unroll
        for (int t=0;t<5;t++){
            z5[t] = hb[(t-2)*PSZ];
            y5[t] = hb[(t-2)*PSY];
            x5[t] = hb[(t-2)];
        }
        #pragma unroll
        for (int o=0;o<2;o++){
            const float* wp1 = w1 + ((oc0+o)*32+ic)*27;
            float a = a1[o];
            #pragma unroll
            for (int t=0;t<27;t++) a += wp1[t]*in3[t];
            a1[o]=a;
            const float* wp2 = w2 + ((oc0+o)*32+ic)*5;
            const float* wp3 = w3 + ((oc0+o)*32+ic)*5;
            const float* wp4 = w4 + ((oc0+o)*32+ic)*5;
            float s2a=a2[o], s3a=a3[o], s4a=a4[o];
            #pragma unroll
            for (int t=0;t<5;t++){
                s2a += wp2[t]*z5[t];
                s3a += wp3[t]*y5[t];
                s4a += wp4[t]*x5[t];
            }
            a2[o]=s2a; a3[o]=s3a; a4[o]=s4a;
        }
    }
    #pragma unroll
    for (int o=0;o<2;o++){
        e[(oc0+o)*L+l]      = a1[o];
        e[(16+oc0+o)*L+l]   = a2[o];
        e[(32+oc0+o)*L+l]   = a3[o];
        e[(48+oc0+o)*L+l]   = a4[o];
    }
}

// elk5 (1x1x1, 64->32) + residual + stats
__global__ void k_elk5(const float* __restrict__ e, const float* __restrict__ hres,
                       const float* __restrict__ w, const float* __restrict__ b,
                       float* __restrict__ h2, float* __restrict__ st)
{
    int oc = blockIdx.x; int l0 = blockIdx.y*(L/8);
    float s=0.f, s2=0.f;
    for (int l=l0+threadIdx.x; l<l0+L/8; l+=256){
        float acc = b[oc];
        #pragma unroll
        for (int m=0;m<64;m++) acc += w[oc*64+m]*e[m*L+l];
        acc += hres[oc*L+l];
        h2[oc*L+l]=acc; s+=acc; s2+=acc*acc;
    }
    block_accum2(s,s2, st+oc, st+32+oc);
}

// ---------------- fusion ----------------

__global__ void k_pool(const float* __restrict__ h3, const float* __restrict__ xm,
                       float* __restrict__ pooled)
{
    int fc = blockIdx.x; int l0 = blockIdx.y*(L/8);
    const float* src = (fc&1) ? xm + (fc>>1)*L : h3 + (fc>>1)*L;
    float s=0.f;
    for (int l=l0+threadIdx.x; l<l0+L/8; l+=256) s += src[l];
    #pragma unroll
    for (int m=1;m<64;m<<=1) s += __shfl_xor(s,m,64);
    __shared__ float red[4];
    int lane = threadIdx.x&63, wid = threadIdx.x>>6;
    if (lane==0) red[wid]=s;
    __syncthreads();
    if (threadIdx.x==0) atomicAdd(pooled+fc, red[0]+red[1]+red[2]+red[3]);
}

__global__ void k_attn(const float* __restrict__ pooled, const float* __restrict__ aw,
                       float* __restrict__ attn)
{
    __shared__ float pl[64];
    int t = threadIdx.x;
    pl[t] = pooled[t]*(1.0f/(float)L);
    __syncthreads();
    float acc=0.f;
    #pragma unroll
    for (int c=0;c<64;c++) acc += aw[t*64+c]*pl[c];
    attn[t] = sigm(sigm(acc));
}

// final: conv2 gate (xcat order), attn scale, 1x1 conv1 (fused/interleaved order), chunked accs
__global__ __launch_bounds__(256,2)
void k_final(const float* __restrict__ h3, const float* __restrict__ xm,
             const float* __restrict__ attn, const float* __restrict__ w1,
             const float* __restrict__ c2w, const float* __restrict__ c2b,
             float* __restrict__ out)
{
    int l = blockIdx.x*blockDim.x + threadIdx.x;
    int o0 = blockIdx.y*16;
    float acc[16];
    #pragma unroll
    for (int o=0;o<16;o++) acc[o]=0.f;
    float a2 = c2b[0];
    #pragma unroll
    for (int i=0;i<32;i++){
        float hv = h3[i*L+l];
        float xv = xm[i*L+l];
        a2 += c2w[i]*hv + c2w[32+i]*xv;   // xcat order: [h3(0..31), xm(0..31)]
        float fh = hv*attn[2*i];          // fused (interleaved) order channel 2i
        float fx = xv*attn[2*i+1];        //                       channel 2i+1
        #pragma unroll
        for (int o=0;o<16;o++)
            acc[o] += w1[(o0+o)*64 + 2*i]*fh + w1[(o0+o)*64 + 2*i+1]*fx;
    }
    float at2 = sigm(a2);
    #pragma unroll
    for (int o=0;o<16;o++) out[(o0+o)*L+l] = acc[o]*at2;
}

// ---------------- launch ----------------

extern "C" void kernel_launch(void* const* d_in, const int* in_sizes, int n_in,
                              void* d_out, int out_size, void* d_ws, size_t ws_size,
                              hipStream_t stream)
{
    const float* x         = (const float*)d_in[0];
    const float* ln_g      = (const float*)d_in[1];
    const float* ln_b      = (const float*)d_in[2];
    const float* in_proj_w = (const float*)d_in[3];
    const float* conv1d_w  = (const float*)d_in[4];
    const float* conv1d_b  = (const float*)d_in[5];
    const float* x_proj_w  = (const float*)d_in[6];
    const float* dt_proj_w = (const float*)d_in[7];
    const float* dt_proj_b = (const float*)d_in[8];
    const float* A_log     = (const float*)d_in[9];
    const float* D_f       = (const float*)d_in[10];
    const float* conv1db_w = (const float*)d_in[11];
    const float* conv1db_b = (const float*)d_in[12];
    const float* x_projb_w = (const float*)d_in[13];
    const float* dt_projb_w= (const float*)d_in[14];
    const float* dt_projb_b= (const float*)d_in[15];
    const float* Ab_log    = (const float*)d_in[16];
    const float* D_b       = (const float*)d_in[17];
    const float* out_proj_w= (const float*)d_in[18];
    const float* cp1_w     = (const float*)d_in[19];
    const float* cp1_b     = (const float*)d_in[20];
    const float* elk1_w    = (const float*)d_in[21];
    const float* elk1_b    = (const float*)d_in[22];
    const float* elk2_w    = (const float*)d_in[23];
    const float* elk2_b    = (const float*)d_in[24];
    const float* elk3_w    = (const float*)d_in[25];
    const float* elk3_b    = (const float*)d_in[26];
    const float* elk4_w    = (const float*)d_in[27];
    const float* elk4_b    = (const float*)d_in[28];
    const float* elk5_w    = (const float*)d_in[29];
    const float* elk5_b    = (const float*)d_in[30];
    const float* cp2_w     = (const float*)d_in[31];
    const float* cp2_b     = (const float*)d_in[32];
    const float* atten_w   = (const float*)d_in[33];
    const float* conv1_w   = (const float*)d_in[34];
    const float* conv2_w   = (const float*)d_in[35];
    const float* conv2_b   = (const float*)d_in[36];

    float* ws = (float*)d_ws;
    // workspace layout (floats)
    float* XI  = ws + 0;          // [64][L] (dead after k_conv_proj; reused as H1P)
    float* Z   = ws + 1048576;    // [L][64]
    float* UF  = ws + 2097152;    // [L][64]
    float* UB  = ws + 3145728;
    float* DLF = ws + 4194304;    // [L][64]
    float* DLB = ws + 5242880;
    float* BF  = ws + 6291456;    // [L][16]
    float* CF  = ws + 6553600;
    float* BB  = ws + 6815744;
    float* CB  = ws + 7077888;
    float* CHA = ws + 7340032;    // [2][NC][1024]
    float* CHB = ws + 7864320;
    float* HST = ws + 8388608;
    float* YF  = ws + 8912896;    // [L][64]
    float* YB  = ws + 9961472;
    float* XM  = ws + 11010048;   // [32][L]
    float* H1  = ws + 11534336;   // [32][L]
    float* E4  = ws + 12058624;   // [64][L]
    float* H2  = ws + 13107200;
    float* H3  = ws + 13631488;
    float* ST  = ws + 14155776;   // stats1[64] stats2[64] stats3[64] pooled[64] attn[64]
    float* H1P = XI;              // padded H1: 32*PCH = 829440 floats < 1048576 (XI region)

    hipMemsetAsync(ST, 0, 256*sizeof(float), stream);

    // mamba branch (pre-scan) — uses XI
    k_ln_proj<<<dim3(L/256,4), 256, 0, stream>>>(x, ln_g, ln_b, in_proj_w, XI, Z);
    k_conv_proj<<<dim3(L/256,2), 256, 0, stream>>>(XI,
        conv1d_w, conv1d_b, x_proj_w, dt_proj_w, dt_proj_b,
        conv1db_w, conv1db_b, x_projb_w, dt_projb_w, dt_projb_b,
        UF, DLF, BF, CF, UB, DLB, BB, CB);
    k_scan1<<<dim3(NC,2), 1024, 0, stream>>>(DLF, BF, UF, DLB, BB, UB, A_log, Ab_log, CHA, CHB);
    k_scan_agg<<<2, 1024, 0, stream>>>(CHA, CHB, HST);
    k_scan2<<<dim3(NC,2), 1024, 0, stream>>>(DLF, BF, CF, UF, DLB, BB, CB, UB,
                                             A_log, Ab_log, D_f, D_b, HST, YF, YB);
    k_combine<<<dim3(L/256,2), 256, 0, stream>>>(YF, YB, Z, out_proj_w, XM);

    // conv3d branch — XI is now dead, reuse as padded H1
    k_conv1x1<<<dim3(32,8), 256, 0, stream>>>(x, cp1_w, cp1_b, H1, ST);
    hipMemsetAsync(H1P, 0, 32*PCH*sizeof(float), stream);
    k_norm_pad<<<dim3(32,8), 256, 0, stream>>>(H1, ST, H1P);
    k_elk<<<dim3(L/256,8), 256, 0, stream>>>(H1P, elk1_w, elk1_b, elk2_w, elk2_b,
                                             elk3_w, elk3_b, elk4_w, elk4_b, E4);
    k_elk5<<<dim3(32,8), 256, 0, stream>>>(E4, H1, elk5_w, elk5_b, H2, ST+64);
    k_norm<<<dim3(32,8), 256, 0, stream>>>(H2, ST+64);
    k_conv1x1<<<dim3(32,8), 256, 0, stream>>>(H2, cp2_w, cp2_b, H3, ST+128);
    k_norm<<<dim3(32,8), 256, 0, stream>>>(H3, ST+128);

    // fusion
    k_pool<<<dim3(64,8), 256, 0, stream>>>(H3, XM, ST+192);
    k_attn<<<1, 64, 0, stream>>>(ST+192, atten_w, ST+256);
    k_final<<<dim3(L/256,4), 256, 0, stream>>>(H3, XM, ST+256, conv1_w, conv2_w, conv2_b,
                                               (float*)d_out);
}